// Round 6
// baseline (114.242 us; speedup 1.0000x reference)
//
#include <hip/hip_runtime.h>

// x:  [N=4, C=256, H=56, W=56] fp32
// w1: [N, 1, 32, 9,  H, W]     (3x3, pad 1)
// w2: [N, 1, 32, 25, H, W]     (5x5, pad 2)
// out:[N, 2, 1, C, H, W]
// out[n,b,c,h,w] = sum_p wB[n, c%32, p, h, w] * x[n, c, h+dh, w+dw] (zero pad)
//
// R6: all-float4 version of R5. Thread = (row, 4-px float4 strip) x 4 groups.
// Per thread: 34 global float4 weight loads (16B/lane, halves VMEM issue vs
// R5's float2), 40 ds_read_b128 for x windows, 544 FMA. LDS layout shifted:
// x col c at slot c+2 so an 8-float window for strip wb=4s starts at slot 4s
// -> 16B aligned -> real ds_read_b128. Block = (n, v, gsel, 14-row tile),
// grid 1024 = 4 blocks/CU, 196/256 threads compute. LDS 18.4 KB.

#define N_  4
#define C_  256
#define H_  56
#define W_  56
#define HW_ 3136
#define WC_ 32

#define TILE    14
#define LROWS   18   // TILE + 4 halo rows
#define LSTRIDE 64   // x col c -> slot c+2; slots 0,1 & 58,59 are zero halo

__global__ __launch_bounds__(256) void lconv_kernel(
    const float* __restrict__ x,
    const float* __restrict__ w1,
    const float* __restrict__ w2,
    float* __restrict__ out)
{
    __shared__ float lds[4 * LROWS * LSTRIDE];   // 18432 B

    const int b    = blockIdx.x;        // 0..1023
    const int tile = b & 3;
    const int gsel = (b >> 2) & 1;
    const int v    = (b >> 3) & 31;
    const int n    = b >> 8;
    const int r0   = tile * TILE;
    const int nv   = n * WC_ + v;
    const int tid  = threadIdx.x;

    // ---- stage x: 4 planes x 18 rows x 56 cols; zero OOB rows ----
    for (int idx = tid; idx < 4 * LROWS * 14; idx += 256) {
        const int c4 = idx % 14;
        const int t2 = idx / 14;
        const int lr = t2 % LROWS;
        const int pl = t2 / LROWS;
        const int gr = r0 - 2 + lr;
        float4 val = make_float4(0.f, 0.f, 0.f, 0.f);
        if (gr >= 0 && gr < H_) {
            const int ch = gsel * 128 + pl * 32 + v;
            val = *(const float4*)(x + (size_t)(n * C_ + ch) * HW_ + gr * W_ + c4 * 4);
        }
        float* lp = &lds[(pl * LROWS + lr) * LSTRIDE + 4 * c4 + 2];
        *(float2*)(lp)     = make_float2(val.x, val.y);
        *(float2*)(lp + 2) = make_float2(val.z, val.w);
    }
    // zero column halos: slots 0,1 (x cols -2,-1) and 58,59 (x cols 56,57)
    for (int idx = tid; idx < 4 * LROWS * 4; idx += 256) {
        const int k  = idx & 3;
        const int t2 = idx >> 2;
        const int lr = t2 % LROWS;
        const int pl = t2 / LROWS;
        const int slot = (k < 2) ? k : (56 + k);
        lds[(pl * LROWS + lr) * LSTRIDE + slot] = 0.f;
    }
    __syncthreads();

    if (tid >= TILE * 14) return;       // 196 compute threads; no barriers below

    const int row = tid / 14;           // 0..13
    const int s   = tid % 14;
    const int wb  = 4 * s;              // 0,4,...,52
    const int h   = r0 + row;           // < 56 always
    const int hw  = h * W_ + wb;

    const float* w1t = w1 + (size_t)nv * 9  * HW_ + hw;
    const float* w2t = w2 + (size_t)nv * 25 * HW_ + hw;

    float a1[4][4], a2[4][4];
    #pragma unroll
    for (int g = 0; g < 4; ++g)
        #pragma unroll
        for (int p = 0; p < 4; ++p) { a1[g][p] = 0.f; a2[g][p] = 0.f; }

    #pragma unroll 1
    for (int di = 0; di < 5; ++di) {
        const bool inner = (di >= 1) && (di <= 3);

        float wr2[5][4];
        #pragma unroll
        for (int dj = 0; dj < 5; ++dj) {
            const float4 t = *(const float4*)(w2t + (size_t)(di * 5 + dj) * HW_);
            wr2[dj][0] = t.x; wr2[dj][1] = t.y; wr2[dj][2] = t.z; wr2[dj][3] = t.w;
        }
        float wr1[3][4];
        #pragma unroll
        for (int dj = 0; dj < 3; ++dj)
            #pragma unroll
            for (int p = 0; p < 4; ++p) wr1[dj][p] = 0.f;
        if (inner) {
            #pragma unroll
            for (int dj = 0; dj < 3; ++dj) {
                const float4 t = *(const float4*)(w1t + (size_t)((di - 1) * 3 + dj) * HW_);
                wr1[dj][0] = t.x; wr1[dj][1] = t.y; wr1[dj][2] = t.z; wr1[dj][3] = t.w;
            }
        }

        #pragma unroll
        for (int g = 0; g < 4; ++g) {
            // window: x cols wb-2 .. wb+5 -> slots wb .. wb+7 (16B aligned)
            const float* lp = &lds[(g * LROWS + row + di) * LSTRIDE + wb];
            const float4 xa = *(const float4*)(lp);
            const float4 xb4 = *(const float4*)(lp + 4);
            const float xw[8] = {xa.x, xa.y, xa.z, xa.w, xb4.x, xb4.y, xb4.z, xb4.w};

            #pragma unroll
            for (int dj = 0; dj < 5; ++dj)
                #pragma unroll
                for (int p = 0; p < 4; ++p)
                    a2[g][p] += wr2[dj][p] * xw[p + dj];
            if (inner) {
                #pragma unroll
                for (int dj = 0; dj < 3; ++dj)
                    #pragma unroll
                    for (int p = 0; p < 4; ++p)
                        a1[g][p] += wr1[dj][p] * xw[p + dj + 1];
            }
        }
    }

    const int c0 = gsel * 128 + v;
    float* o1 = out + ((size_t)(n * 2 + 0) * C_ + c0) * HW_ + hw;
    float* o2 = out + ((size_t)(n * 2 + 1) * C_ + c0) * HW_ + hw;
    #pragma unroll
    for (int g = 0; g < 4; ++g) {
        *(float4*)(o1 + (size_t)g * WC_ * HW_) =
            make_float4(a1[g][0], a1[g][1], a1[g][2], a1[g][3]);
        *(float4*)(o2 + (size_t)g * WC_ * HW_) =
            make_float4(a2[g][0], a2[g][1], a2[g][2], a2[g][3]);
    }
}

extern "C" void kernel_launch(void* const* d_in, const int* in_sizes, int n_in,
                              void* d_out, int out_size, void* d_ws, size_t ws_size,
                              hipStream_t stream) {
    const float* x  = (const float*)d_in[0];
    const float* w1 = (const float*)d_in[1];
    const float* w2 = (const float*)d_in[2];
    float* out = (float*)d_out;

    dim3 grid(4 * 2 * 32 * 4), block(256);   // 1024 blocks = 4/CU
    hipLaunchKernelGGL(lconv_kernel, grid, block, 0, stream, x, w1, w2, out);
}